// Round 19
// baseline (35.022 us; speedup 1.0000x reference)
//
#include <hip/hip_runtime.h>

#define DIM 120
#define NB 16            // batch rows per block
#define NBP 20           // padded LDS stride in dwords (b128-aligned)
#define BLOCK 256        // one thread per output row within a tile
#define NG (NB / 4)      // float4 groups along b
#define NXCD 8
#define TILES 3          // consecutive o-tiles per block (57 = 19*3)

// ---- Fused preprocess: diff-based CSR row pointers + packed entries ----
__global__ void pre_kernel(const int* __restrict__ oi, int K, int H,
                           int* __restrict__ row_start,
                           const int* __restrict__ i1, const int* __restrict__ i2,
                           const int* __restrict__ cb, const float* __restrict__ pal,
                           uint2* __restrict__ ent) {
    int k = blockIdx.x * blockDim.x + threadIdx.x;
    if (k < K) {
        uint2 e;
        e.x = (unsigned)i1[k] | ((unsigned)i2[k] << 16);
        e.y = __float_as_uint(pal[cb[k]]);
        ent[k] = e;
        const int cur = oi[k];
        const int prev = (k == 0) ? -1 : oi[k - 1];
        for (int o = prev + 1; o <= cur; ++o) row_start[o] = k;
    } else if (k == K) {
        const int prev = oi[K - 1];
        for (int o = prev + 1; o <= H; ++o) row_start[o] = K;
    }
}

// ---- Main: stage once; sweep 3 consecutive o-tiles; NT stores of tile t
//      drain under tile t+1's k-loop (store/compute pipelining). ----
__global__ __launch_bounds__(BLOCK, 8) void tp_kernel(
    const float* __restrict__ in1, const float* __restrict__ in2,
    const uint2* __restrict__ ent, const int* __restrict__ row_start,
    float* __restrict__ out, int H, int ngrp) {
    // bijective XCD-chunked swizzle over the tile-group dimension
    int g = blockIdx.x;
    {
        const int q = ngrp / NXCD, r = ngrp % NXCD;
        const int xcd = g % NXCD, pos = g / NXCD;
        g = (xcd < r) ? (xcd * (q + 1) + pos) : (r * (q + 1) + (xcd - r) * q + pos);
    }

    __shared__ __align__(16) float s1t[DIM * NBP];
    __shared__ __align__(16) float s2t[DIM * NBP];

    // --- stage NB batch-rows transposed to [d][b] (once per block) ---
    const int b0 = blockIdx.y * NB;
    for (int t = threadIdx.x; t < 2 * DIM * NG; t += BLOCK) {
        const int arr = (t >= DIM * NG);
        const int c = arr ? t - DIM * NG : t;
        const int d = c % DIM;
        const int gg = c / DIM;
        const float* __restrict__ src = arr ? in2 : in1;
        const size_t base = (size_t)(b0 + 4 * gg) * DIM + d;
        float4 v;
        v.x = src[base + 0 * DIM];
        v.y = src[base + 1 * DIM];
        v.z = src[base + 2 * DIM];
        v.w = src[base + 3 * DIM];
        float* dst = arr ? s2t : s1t;
        *(float4*)(dst + d * NBP + 4 * gg) = v;
    }
    __syncthreads();

    // --- sweep TILES consecutive o-tiles; no barriers between tiles ---
    for (int t = 0; t < TILES; ++t) {
        const int o = (g * TILES + t) * BLOCK + (int)threadIdx.x;
        if (o >= H) continue;
        const int k0 = row_start[o];
        const int k1 = row_start[o + 1];

        float acc[NB];
#pragma unroll
        for (int b = 0; b < NB; ++b) acc[b] = 0.0f;

        for (int k = k0; k < k1; ++k) {
            const uint2 e = ent[k];
            const float4* __restrict__ pa = (const float4*)(s1t + (e.x & 0xffffu) * NBP);
            const float4* __restrict__ pc = (const float4*)(s2t + (e.x >> 16) * NBP);
            const float v = __uint_as_float(e.y);
#pragma unroll
            for (int j = 0; j < NG; ++j) {
                const float4 x4 = pa[j];
                const float4 y4 = pc[j];
                acc[4 * j + 0] = fmaf(v * x4.x, y4.x, acc[4 * j + 0]);
                acc[4 * j + 1] = fmaf(v * x4.y, y4.y, acc[4 * j + 1]);
                acc[4 * j + 2] = fmaf(v * x4.z, y4.z, acc[4 * j + 2]);
                acc[4 * j + 3] = fmaf(v * x4.w, y4.w, acc[4 * j + 3]);
            }
        }

        // fire NT stores; next tile's compute overlaps the drain
#pragma unroll
        for (int b = 0; b < NB; ++b)
            __builtin_nontemporal_store(acc[b], &out[(size_t)(b0 + b) * H + o]);
    }
}

extern "C" void kernel_launch(void* const* d_in, const int* in_sizes, int n_in,
                              void* d_out, int out_size, void* d_ws, size_t ws_size,
                              hipStream_t stream) {
    const float* in1 = (const float*)d_in[0];
    const float* in2 = (const float*)d_in[1];
    const float* pal = (const float*)d_in[2];
    const int*   i1  = (const int*)d_in[3];
    const int*   i2  = (const int*)d_in[4];
    const int*   oi  = (const int*)d_in[5];
    const int*   cb  = (const int*)d_in[6];

    const int K = in_sizes[3];
    const int B = in_sizes[0] / DIM;   // 2048
    const int H = out_size / B;        // 14400

    uint2* ent = (uint2*)d_ws;
    int* row_start = (int*)((char*)d_ws + (size_t)K * sizeof(uint2));

    pre_kernel<<<(K + 1 + 255) / 256, 256, 0, stream>>>(oi, K, H, row_start,
                                                        i1, i2, cb, pal, ent);

    const int nbx = (H + BLOCK - 1) / BLOCK;          // 57
    const int ngrp = (nbx + TILES - 1) / TILES;       // 19
    dim3 grid(ngrp, B / NB);
    tp_kernel<<<grid, BLOCK, 0, stream>>>(in1, in2, ent, row_start,
                                          (float*)d_out, H, ngrp);
}